// Round 5
// baseline (453.519 us; speedup 1.0000x reference)
//
#include <hip/hip_runtime.h>
#include <math.h>

// RoutingLayer fused via split-fp16 MFMA emulation of fp32 GEMM.
// routing = x@w_gate + noise*(softplus(x@w_noise)+0.01); out = scatter(softmax(top2)).
// x: 32768x2048 fp32, w_*: 2048x64 fp32, noise: 32768x64, out: 32768x64.
//
// R5: barrier-free all-register K-loop. R4 was latency-bound (2 barriers +
// LDS conversion round-trip per chunk; MfmaUtil 12%, VALU 19%, HBM 11%).
// New structure: wave = 16 rows x all 128 cols (8 ntiles).
//  - A: direct global loads in frag order (lane -> x[row0+(lane&15)]
//    [c*32+(lane>>4)*8..+8]), fp32->fp16 split in registers. x read once.
//  - B: direct global loads of presplit frag blocks (1KB contiguous, L2-hot).
//  - No LDS, no __syncthreads anywhere. Pipeline: B dbuf (128 VGPR),
//    A quad-buf (2-chunk lookahead covers ~900cy HBM latency).
//  - Epilogue: register-local gate/noise combine, butterfly top-2 over the
//    16 col-lanes, direct coalesced stores.

typedef _Float16 half8v __attribute__((ext_vector_type(8)));
typedef float f32x4 __attribute__((ext_vector_type(4)));

constexpr int DIMK = 2048;
constexpr int NEXP = 64;
constexpr int NCH  = DIMK / 32;   // 64 k-chunks

__device__ __forceinline__ bool gt_pair(float a, int ia, float b, int ib) {
    return (a > b) || (a == b && ia < ib);   // jax top_k: lower index wins ties
}

// ---- pre-kernel: split w' = 65536*[wg|wn] into 2 fp16 planes in B-frag order.
// ws layout: [chunk c][plane p][ntile t][lane][8 halfs]  (1KB per (c,p,t))
// B-frag (16x16x32): lane holds B[k = c*32 + (lane>>4)*8 + j][n = t*16 + (lane&15)]
__global__ __launch_bounds__(256)
void presplit_kernel(const float* __restrict__ wg, const float* __restrict__ wn,
                     _Float16* __restrict__ wsB)
{
    int gid  = blockIdx.x * 256 + threadIdx.x;   // 0..32767 = (c, t, lane)
    int lane = gid & 63;
    int t    = (gid >> 6) & 7;
    int c    = gid >> 9;
    int n    = t * 16 + (lane & 15);
    int kb   = c * 32 + ((lane >> 4) << 3);
    const float* src = (n < NEXP) ? (wg + n) : (wn + (n - NEXP));
    half8v h1, h2;
    #pragma unroll
    for (int j = 0; j < 8; ++j) {
        float w = src[(size_t)(kb + j) * NEXP] * 65536.0f;
        _Float16 a = (_Float16)w;
        h1[j] = a;
        h2[j] = (_Float16)(w - (float)a);
    }
    // f = p*8 + t; linear offset (c*16 + f)*512 + lane*8
    *(half8v*)(wsB + ((size_t)c * 16 + 0 + t) * 512 + lane * 8) = h1;
    *(half8v*)(wsB + ((size_t)c * 16 + 8 + t) * 512 + lane * 8) = h2;
}

// ---- main kernel: 4 waves/block, each wave = 16 rows x 128 cols, no LDS.
__global__ __launch_bounds__(256, 2)
void routing_mfma(const float* __restrict__ x, const _Float16* __restrict__ wsB,
                  const float* __restrict__ noise, float* __restrict__ out)
{
    const int tid  = threadIdx.x;
    const int lane = tid & 63;
    const int w    = tid >> 6;
    const int cidx = lane & 15;          // A row / C col within tile
    const int q    = lane >> 4;          // k-quad / C row-quad
    const int row0 = blockIdx.x * 64 + w * 16;   // wave's first row

    const float* __restrict__ xbase =
        x + (size_t)(row0 + cidx) * DIMK + q * 8;
    const _Float16* __restrict__ bbase = wsB + (size_t)lane * 8;

    f32x4 acc[8] = {};                   // nt 0..3 gate, 4..7 noise

    float4 Abuf[4][2];                   // quad-buffered A (fp32)
    half8v Bbuf[2][16];                  // double-buffered B frags (f = p*8+t)

#define LOAD_A(c, buf)                                                   \
    do {                                                                 \
        Abuf[buf][0] = *(const float4*)(xbase + (c) * 32);               \
        Abuf[buf][1] = *(const float4*)(xbase + (c) * 32 + 4);           \
    } while (0)
#define LOAD_B(c, buf)                                                   \
    do {                                                                 \
        _Pragma("unroll")                                                \
        for (int f = 0; f < 16; ++f)                                     \
            Bbuf[buf][f] = *(const half8v*)(                             \
                bbase + ((size_t)(c) * 16 + f) * 512);                   \
    } while (0)

    LOAD_A(0, 0);
    LOAD_B(0, 0);
    LOAD_A(1, 1);

    #pragma unroll 4
    for (int c = 0; c < NCH; ++c) {
        if (c + 1 < NCH) LOAD_B(c + 1, (c + 1) & 1);
        if (c + 2 < NCH) LOAD_A(c + 2, (c + 2) & 3);

        // fp32 -> fp16 hi/lo split in registers (x' = 1024*x)
        const float4 a0 = Abuf[c & 3][0], a1 = Abuf[c & 3][1];
        const float fv[8] = {a0.x, a0.y, a0.z, a0.w, a1.x, a1.y, a1.z, a1.w};
        half8v h1, h2;
        #pragma unroll
        for (int j = 0; j < 8; ++j) {
            float v = fv[j] * 1024.0f;
            _Float16 hi = (_Float16)v;
            h1[j] = hi;
            h2[j] = (_Float16)(v - (float)hi);
        }
        const half8v* B = Bbuf[c & 1];
        #pragma unroll
        for (int nt = 0; nt < 8; ++nt) {
            acc[nt] = __builtin_amdgcn_mfma_f32_16x16x32_f16(
                h1, B[nt], acc[nt], 0, 0, 0);          // x1*w1
            acc[nt] = __builtin_amdgcn_mfma_f32_16x16x32_f16(
                h1, B[nt + 8], acc[nt], 0, 0, 0);      // x1*w2
            acc[nt] = __builtin_amdgcn_mfma_f32_16x16x32_f16(
                h2, B[nt], acc[nt], 0, 0, 0);          // x2*w1
        }
    }
#undef LOAD_A
#undef LOAD_B

    // ---- epilogue (no LDS): C/D layout col=cidx, row=q*4+reg.
    // Lane has, for each reg r: row row0+q*4+r, gate experts {nt*16+cidx},
    // noise counterpart in acc[nt+4]. Unscale 2^-26 (1024*65536).
    const float s = 0x1p-26f;
    #pragma unroll
    for (int r = 0; r < 4; ++r) {
        const int row = row0 + q * 4 + r;
        float v1 = -INFINITY, v2 = -INFINITY;
        int i1 = 0, i2 = 0;
        #pragma unroll
        for (int nt = 0; nt < 4; ++nt) {
            int e = nt * 16 + cidx;
            float nz   = noise[(size_t)row * NEXP + e];
            float gate = acc[nt][r] * s;
            float nv   = acc[nt + 4][r] * s;
            float sp   = fmaxf(nv, 0.f) + log1pf(expf(-fabsf(nv)));
            float rv   = gate + nz * (sp + 0.01f);
            if (rv > v1)      { v2 = v1; i2 = i1; v1 = rv; i1 = e; }
            else if (rv > v2) { v2 = rv; i2 = e; }
        }
        // butterfly across the 16 cidx lanes (masks 1,2,4,8 stay within q-group)
        #pragma unroll
        for (int mm = 1; mm <= 8; mm <<= 1) {
            float b1 = __shfl_xor(v1, mm); int ib1 = __shfl_xor(i1, mm);
            float b2 = __shfl_xor(v2, mm); int ib2 = __shfl_xor(i2, mm);
            if (gt_pair(b1, ib1, v1, i1)) {
                float o1 = v1; int oi1 = i1;
                v1 = b1; i1 = ib1;
                if (gt_pair(b2, ib2, o1, oi1)) { v2 = b2; i2 = ib2; }
                else                           { v2 = o1; i2 = oi1; }
            } else if (gt_pair(b1, ib1, v2, i2)) {
                v2 = b1; i2 = ib1;
            }
        }
        // 2-way softmax; every lane writes its 4-expert segment of the row
        float t  = expf(v2 - v1);        // <= 1
        float g1 = 1.f / (1.f + t);
        float g2 = t * g1;
        int e0 = cidx * 4;
        float4 o;
        o.x = (e0 + 0 == i1) ? g1 : ((e0 + 0 == i2) ? g2 : 0.f);
        o.y = (e0 + 1 == i1) ? g1 : ((e0 + 1 == i2) ? g2 : 0.f);
        o.z = (e0 + 2 == i1) ? g1 : ((e0 + 2 == i2) ? g2 : 0.f);
        o.w = (e0 + 3 == i1) ? g1 : ((e0 + 3 == i2) ? g2 : 0.f);
        *(float4*)(out + (size_t)row * NEXP + e0) = o;
    }
}

extern "C" void kernel_launch(void* const* d_in, const int* in_sizes, int n_in,
                              void* d_out, int out_size, void* d_ws, size_t ws_size,
                              hipStream_t stream) {
    const float* x     = (const float*)d_in[0];
    const float* wg    = (const float*)d_in[1];
    const float* wn    = (const float*)d_in[2];
    const float* noise = (const float*)d_in[3];
    float* out = (float*)d_out;
    _Float16* wsB = (_Float16*)d_ws;   // 64*16*512*2B = 1 MB

    presplit_kernel<<<dim3(128), 256, 0, stream>>>(wg, wn, wsB);

    const int Brows = in_sizes[0] / DIMK;          // 32768
    dim3 grid(Brows / 64);                         // 512 blocks -> 2/CU
    routing_mfma<<<grid, 256, 0, stream>>>(x, wsB, noise, out);
}